// Round 2
// baseline (1398.595 us; speedup 1.0000x reference)
//
#include <hip/hip_runtime.h>
#include <stdint.h>

// out[8192,4096] = x[8192,4096] @ (A[4096,16] @ B[16,4096]), ALL FP32.
// Fused low-rank. v3: kill the per-K-step accumulator spill.
//   Evidence (v1->v2): excess HBM fetch+write per thread halved when acc
//   halved (64->32 floats) => acc is spilled/reloaded once per K-step.
//   Cause: __launch_bounds__(256,4) only sets MIN waves/EU; scheduler
//   squeezed to 8 waves/EU (64-VGPR target) and spilled to get there.
//   Fix: amdgpu_waves_per_eu(4,4) pins the target => 128-VGPR budget.
//   Also: inner loop consumes A in 2x float4 halves (peak live ~60 regs),
//   nontemporal X loads / O stores (streamed once; keep L2 for A/B).
// Ideal traffic ~268 MB => ~43 us floor at 6.3 TB/s achievable.

typedef float f32x4 __attribute__((ext_vector_type(4)));

#define KD 4096   // D_IN
#define ND 4096   // D_OUT
#define NR 16     // rank
#define BLK 256
#define RPW 2     // rows per wave (concurrent)
#define MB 8      // rows per block = 4 waves * RPW

// ACC[B..B+7] += XF * {VA, VB}
#define FMA8(ACC, XF, VA, VB, B)                              \
    ACC[B + 0] = fmaf((XF), VA[0], ACC[B + 0]);               \
    ACC[B + 1] = fmaf((XF), VA[1], ACC[B + 1]);               \
    ACC[B + 2] = fmaf((XF), VA[2], ACC[B + 2]);               \
    ACC[B + 3] = fmaf((XF), VA[3], ACC[B + 3]);               \
    ACC[B + 4] = fmaf((XF), VB[0], ACC[B + 4]);               \
    ACC[B + 5] = fmaf((XF), VB[1], ACC[B + 5]);               \
    ACC[B + 6] = fmaf((XF), VB[2], ACC[B + 6]);               \
    ACC[B + 7] = fmaf((XF), VB[3], ACC[B + 7]);

__global__ __attribute__((amdgpu_flat_work_group_size(BLK, BLK),
                          amdgpu_waves_per_eu(4, 4)))
void lora_fused(const float* __restrict__ X,
                const float* __restrict__ A,
                const float* __restrict__ Bm,
                float* __restrict__ O)
{
    __shared__ float t_s[MB][NR];

    const int tid  = threadIdx.x;
    const int wv   = tid >> 6;
    const int lane = tid & 63;
    const size_t m0 = (size_t)blockIdx.x * MB;
    const int row0 = wv * RPW;

    // ---------------- Phase A: T = X @ A ----------------
    float acc0[NR], acc1[NR];
    #pragma unroll
    for (int r = 0; r < NR; ++r) { acc0[r] = 0.f; acc1[r] = 0.f; }

    const float* xp0 = X + (m0 + row0) * (size_t)KD;
    const float* xp1 = xp0 + KD;

    #pragma unroll 1
    for (int s = 0; s < KD / 256; ++s) {         // 16 steps; lane owns 4 consecutive k
        const int k0 = s * 256 + lane * 4;
        const f32x4 x0 = __builtin_nontemporal_load(
            reinterpret_cast<const f32x4*>(xp0 + k0));
        const f32x4 x1 = __builtin_nontemporal_load(
            reinterpret_cast<const f32x4*>(xp1 + k0));

        #pragma unroll
        for (int j = 0; j < 4; ++j) {
            const float* ap = A + (size_t)(k0 + j) * NR;
            const float xf0 = x0[j];
            const float xf1 = x1[j];
            // half 1: r = 0..7
            {
                const f32x4 a0 = *reinterpret_cast<const f32x4*>(ap + 0);
                const f32x4 a1 = *reinterpret_cast<const f32x4*>(ap + 4);
                FMA8(acc0, xf0, a0, a1, 0)
                FMA8(acc1, xf1, a0, a1, 0)
            }
            // half 2: r = 8..15
            {
                const f32x4 a2 = *reinterpret_cast<const f32x4*>(ap + 8);
                const f32x4 a3 = *reinterpret_cast<const f32x4*>(ap + 12);
                FMA8(acc0, xf0, a2, a3, 8)
                FMA8(acc1, xf1, a2, a3, 8)
            }
        }
    }

    // Butterfly reduce across the 64-lane wave
    #pragma unroll
    for (int off = 32; off > 0; off >>= 1) {
        #pragma unroll
        for (int r = 0; r < NR; ++r) {
            acc0[r] += __shfl_xor(acc0[r], off, 64);
            acc1[r] += __shfl_xor(acc1[r], off, 64);
        }
    }

    if (lane == 0) {
        #pragma unroll
        for (int r = 0; r < NR; ++r) {
            t_s[row0 + 0][r] = acc0[r];
            t_s[row0 + 1][r] = acc1[r];
        }
    }
    __syncthreads();

    // ---------------- Phase B: O = T @ B ----------------
    #pragma unroll 1
    for (int p = 0; p < ND / (BLK * 4); ++p) {   // 4 passes, 4 cols/thread
        const int j0 = p * (BLK * 4) + tid * 4;

        f32x4 b[NR];
        #pragma unroll
        for (int r = 0; r < NR; ++r)
            b[r] = *reinterpret_cast<const f32x4*>(Bm + (size_t)r * ND + j0);

        #pragma unroll
        for (int m = 0; m < MB; ++m) {
            const f32x4 t0 = *reinterpret_cast<const f32x4*>(&t_s[m][0]);
            const f32x4 t1 = *reinterpret_cast<const f32x4*>(&t_s[m][4]);
            const f32x4 t2 = *reinterpret_cast<const f32x4*>(&t_s[m][8]);
            const f32x4 t3 = *reinterpret_cast<const f32x4*>(&t_s[m][12]);

            f32x4 o = {0.f, 0.f, 0.f, 0.f};
            #pragma unroll
            for (int j = 0; j < 4; ++j) {
                o = t0[j] * b[0 + j]  + o;
                o = t1[j] * b[4 + j]  + o;
                o = t2[j] * b[8 + j]  + o;
                o = t3[j] * b[12 + j] + o;
            }
            __builtin_nontemporal_store(
                o, reinterpret_cast<f32x4*>(O + (m0 + m) * (size_t)ND + j0));
        }
    }
}

extern "C" void kernel_launch(void* const* d_in, const int* in_sizes, int n_in,
                              void* d_out, int out_size, void* d_ws, size_t ws_size,
                              hipStream_t stream) {
    const float* X  = (const float*)d_in[0];   // [4,2048,4096] fp32
    const float* A  = (const float*)d_in[1];   // [4096,16]     fp32
    const float* Bm = (const float*)d_in[2];   // [16,4096]     fp32
    float* O = (float*)d_out;                  // [4,2048,4096] fp32
    lora_fused<<<8192 / MB, BLK, 0, stream>>>(X, A, Bm, O);
}

// Round 3
// 303.098 us; speedup vs baseline: 4.6143x; 4.6143x over previous
//
#include <hip/hip_runtime.h>
#include <stdint.h>

// out[8192,4096] = x[8192,4096] @ (A[4096,16] @ B[16,4096]), ALL FP32.
// v4: spill-proof by construction (VGPR allocator pins 64 regs no matter
// what attributes we pass; v1-v3 all leaked 0.5-1.7 GB of scratch traffic).
// Peak live set <= ~48 floats at every program point:
//   Phase A rank-on-lane: lane(kg=l>>2, rq=l&3) accumulates ranks
//     4rq..4rq+3 of its wave's 2 rows over k=16t+kg. acc = 8 floats.
//     A-loads perfectly coalesced (addr = base + t*1024 + lane*16).
//     X reads: 16 consecutive dwords/wave, 4-lane broadcast (64B segment).
//     kg-reduction: 4 shfl_xor rounds.
//   Phase B: B col-chunk (16x512, 32 KB) staged in LDS once per block
//     (B L2 traffic 2.1 GB -> 256 MB); thread owns 1 row x 16 cols/chunk;
//     t[16] in regs, o = float4. All LDS access contiguous-16B or broadcast.
// Ideal HBM ~268 MB -> ~43 us floor; L2 ~1.3 GB -> ~37 us; LDS ~2.3 GB -> ~33 us.

#define KD 4096
#define ND 4096
#define NR 16
#define BLK 256
#define MB 8          // rows per block = 4 waves * 2
#define NCHUNK 512    // Phase-B column chunk (32 KB LDS)

// acc.{x,y,z,w} += xv * a.{x,y,z,w}
#define FMA4(ACC, XV, A4)                         \
    ACC.x = fmaf((XV), (A4).x, ACC.x);            \
    ACC.y = fmaf((XV), (A4).y, ACC.y);            \
    ACC.z = fmaf((XV), (A4).z, ACC.z);            \
    ACC.w = fmaf((XV), (A4).w, ACC.w);

#define RED1(C, OFF) C += __shfl_xor(C, OFF, 64);
#define RED(OFF)                                  \
    RED1(acc0.x, OFF) RED1(acc0.y, OFF)           \
    RED1(acc0.z, OFF) RED1(acc0.w, OFF)           \
    RED1(acc1.x, OFF) RED1(acc1.y, OFF)           \
    RED1(acc1.z, OFF) RED1(acc1.w, OFF)

// o += TV * bs_row[R]   (bp points at bs[0][c4*4], rows are NCHUNK floats apart)
#define FMAB(TV, R)                                                        \
    {                                                                      \
        const float4 b_ = *reinterpret_cast<const float4*>(bp + (R) * NCHUNK); \
        o.x = fmaf((TV), b_.x, o.x);                                       \
        o.y = fmaf((TV), b_.y, o.y);                                       \
        o.z = fmaf((TV), b_.z, o.z);                                       \
        o.w = fmaf((TV), b_.w, o.w);                                       \
    }

__global__ __launch_bounds__(BLK)
void lora_fused(const float* __restrict__ X,
                const float* __restrict__ A,
                const float* __restrict__ Bm,
                float* __restrict__ O)
{
    __shared__ float t_s[MB][NR];
    __shared__ float bs[NR * NCHUNK];   // 32 KB

    const int tid  = threadIdx.x;
    const int wv   = tid >> 6;
    const int lane = tid & 63;
    const int rq   = lane & 3;     // rank quad: ranks 4rq..4rq+3
    const int kg   = lane >> 2;    // k subgroup 0..15
    const size_t m0 = (size_t)blockIdx.x * MB;

    // ---------------- Phase A: T = X @ A (rank-on-lane) ----------------
    const float* xp0 = X + (m0 + 2 * wv) * (size_t)KD + kg;  // k = 16t + kg
    const float* xp1 = xp0 + KD;
    const float* ap  = A + (size_t)kg * NR + rq * 4;         // A[16t+kg][4rq]

    float4 acc0 = {0.f, 0.f, 0.f, 0.f};
    float4 acc1 = {0.f, 0.f, 0.f, 0.f};

    #pragma unroll 4
    for (int t = 0; t < KD / 16; ++t) {
        const float  x0 = xp0[(size_t)t * 16];
        const float  x1 = xp1[(size_t)t * 16];
        const float4 a  = *reinterpret_cast<const float4*>(ap + (size_t)t * (16 * NR));
        FMA4(acc0, x0, a)
        FMA4(acc1, x1, a)
    }

    // reduce across the 16 kg-groups (lane = 4*kg + rq)
    RED(4) RED(8) RED(16) RED(32)

    if (lane < 4) {   // kg == 0, lane == rq
        *reinterpret_cast<float4*>(&t_s[2 * wv + 0][lane * 4]) = acc0;
        *reinterpret_cast<float4*>(&t_s[2 * wv + 1][lane * 4]) = acc1;
    }
    __syncthreads();

    // ---------------- Phase B: O = T @ B (B via LDS chunks) ----------------
    const int m  = tid >> 5;   // row 0..7 (2 rows per wave, broadcast-friendly)
    const int cs = tid & 31;

    const float4 t0 = *reinterpret_cast<const float4*>(&t_s[m][0]);
    const float4 t1 = *reinterpret_cast<const float4*>(&t_s[m][4]);
    const float4 t2 = *reinterpret_cast<const float4*>(&t_s[m][8]);
    const float4 t3 = *reinterpret_cast<const float4*>(&t_s[m][12]);

    float* op = O + (m0 + m) * (size_t)ND;

    #pragma unroll 1
    for (int cc = 0; cc < ND / NCHUNK; ++cc) {
        // stage B[0..15][cc*512 .. +511] -> bs, fully coalesced
        #pragma unroll
        for (int i = 0; i < 8; ++i) {
            const int p   = i * BLK + tid;     // float4 slot 0..2047
            const int row = p >> 7;            // 128 float4 per B row-chunk
            const int c4  = p & 127;
            const float4 v = *reinterpret_cast<const float4*>(
                Bm + (size_t)row * ND + cc * NCHUNK + c4 * 4);
            *reinterpret_cast<float4*>(&bs[p * 4]) = v;
        }
        __syncthreads();

        #pragma unroll
        for (int j = 0; j < 4; ++j) {
            const int c4 = cs + 32 * j;
            const float* bp = &bs[c4 * 4];
            float4 o = {0.f, 0.f, 0.f, 0.f};
            FMAB(t0.x, 0)  FMAB(t0.y, 1)  FMAB(t0.z, 2)  FMAB(t0.w, 3)
            FMAB(t1.x, 4)  FMAB(t1.y, 5)  FMAB(t1.z, 6)  FMAB(t1.w, 7)
            FMAB(t2.x, 8)  FMAB(t2.y, 9)  FMAB(t2.z, 10) FMAB(t2.w, 11)
            FMAB(t3.x, 12) FMAB(t3.y, 13) FMAB(t3.z, 14) FMAB(t3.w, 15)
            *reinterpret_cast<float4*>(op + cc * NCHUNK + c4 * 4) = o;
        }
        __syncthreads();
    }
}

extern "C" void kernel_launch(void* const* d_in, const int* in_sizes, int n_in,
                              void* d_out, int out_size, void* d_ws, size_t ws_size,
                              hipStream_t stream) {
    const float* X  = (const float*)d_in[0];   // [4,2048,4096] fp32
    const float* A  = (const float*)d_in[1];   // [4096,16]     fp32
    const float* Bm = (const float*)d_in[2];   // [16,4096]     fp32
    float* O = (float*)d_out;                  // [4,2048,4096] fp32
    lora_fused<<<8192 / MB, BLK, 0, stream>>>(X, A, Bm, O);
}